// Round 6
// baseline (405.008 us; speedup 1.0000x reference)
//
#include <hip/hip_runtime.h>
#include <hip/hip_bf16.h>
#include <math.h>

// GAT 2-layer forward for MI355X.
// R6: agg kernels re-tiled for wider gathers. agg1: 2 edges/iter, 16B/lane
// (1KB/wave-instr); agg2: 4 edges/iter. Halves per-edge issue slots; agg1 was
// issue-bound (VALUBusy 36%, HBM 47%, 8B/lane loads).

#define FIN 128
#define C1 256   // H*D layer1
#define NH 8
#define HD 32
#define C2 64    // F_out
#define TM1 16
#define CH1 64

__device__ __forceinline__ float blo(unsigned u) { return __uint_as_float(u << 16); }
__device__ __forceinline__ float bhi(unsigned u) { return __uint_as_float(u & 0xffff0000u); }

__global__ void zero_kernel(int* p, int n) {
    int i = blockIdx.x * 256 + threadIdx.x;
    if (i < n) p[i] = 0;
}

// 4 edges/thread: count in-degree AND record each edge's rank within its dst.
__global__ void hist_kernel(const int* __restrict__ ei, int E, int ETOT, int T,
                            int* cnt, int* __restrict__ offs) {
    int base = blockIdx.x * 256 + threadIdx.x;
    if (base >= T) return;              // stride period is T: no duplicates
    int d[4], idx[4], o[4];
    #pragma unroll
    for (int i = 0; i < 4; ++i) {
        int e = base + i * T;
        idx[i] = e;
        d[i] = (e < ETOT) ? ((e < E) ? ei[E + e] : (e - E)) : -1;
    }
    #pragma unroll
    for (int i = 0; i < 4; ++i)
        if (d[i] >= 0) o[i] = atomicAdd(&cnt[d[i]], 1);
    #pragma unroll
    for (int i = 0; i < 4; ++i)
        if (d[i] >= 0) offs[idx[i]] = o[i];
}

// Two-level exclusive scan over cnt[0..n).
__global__ void scan1_kernel(const int* __restrict__ cnt, int n,
                             int* __restrict__ pref, int* __restrict__ bsum) {
    int tid = threadIdx.x, lane = tid & 63, w = tid >> 6;
    int i = blockIdx.x * 256 + tid;
    int v = (i < n) ? cnt[i] : 0;
    int sc = v;
    #pragma unroll
    for (int d = 1; d < 64; d <<= 1) {
        int t = __shfl_up(sc, d, 64);
        if (lane >= d) sc += t;
    }
    __shared__ int ws[4];
    if (lane == 63) ws[w] = sc;
    __syncthreads();
    int woff = 0;
    #pragma unroll
    for (int k = 0; k < 4; ++k) woff += (k < w) ? ws[k] : 0;
    if (i < n) pref[i] = woff + sc - v;
    if (tid == 255) bsum[blockIdx.x] = woff + sc;
}

__global__ void scan2_kernel(int* bsum, int nb) {
    int tid = threadIdx.x, lane = tid & 63, w = tid >> 6;
    int v = (tid < nb) ? bsum[tid] : 0;
    int sc = v;
    #pragma unroll
    for (int d = 1; d < 64; d <<= 1) {
        int t = __shfl_up(sc, d, 64);
        if (lane >= d) sc += t;
    }
    __shared__ int ws[4];
    if (lane == 63) ws[w] = sc;
    __syncthreads();
    int woff = 0;
    #pragma unroll
    for (int k = 0; k < 4; ++k) woff += (k < w) ? ws[k] : 0;
    __syncthreads();
    if (tid < nb) bsum[tid] = woff + sc - v;
}

__global__ void scan3_kernel(const int* __restrict__ pref, const int* __restrict__ bsum,
                             int n, int ETOT, int* __restrict__ rowptr) {
    int i = blockIdx.x * 256 + threadIdx.x;
    if (i < n) rowptr[i] = pref[i] + bsum[blockIdx.x];
    if (i == 0) rowptr[n] = ETOT;
}

// No atomics: pos = rowptr[dst] + offs[e]. 4 edges/thread.
__global__ void scatter_kernel(const int* __restrict__ ei, const int* __restrict__ rowptr,
                               const int* __restrict__ offs, int E, int ETOT, int T,
                               int* __restrict__ colb) {
    int base = blockIdx.x * 256 + threadIdx.x;
    if (base >= T) return;
    #pragma unroll
    for (int i = 0; i < 4; ++i) {
        int e = base + i * T;
        if (e >= ETOT) continue;
        int src, dst;
        if (e < E) { src = ei[e]; dst = ei[E + e]; }
        else       { src = e - E; dst = e - E; }
        colb[rowptr[dst] + offs[e]] = src;
    }
}

// h1 = x @ W1  [N,256] stored bf16, plus a_s1/a_d1 per (node, head) in f32
__global__ __launch_bounds__(256) void gemm1_kernel(
    const float* __restrict__ x, const float* __restrict__ W1,
    const float* __restrict__ att_s, const float* __restrict__ att_d,
    __hip_bfloat16* __restrict__ h1, float* __restrict__ as1, float* __restrict__ ad1, int N) {
    __shared__ float xs[TM1][FIN];
    int tid = threadIdx.x;
    int row0 = blockIdx.x * TM1;
    #pragma unroll
    for (int i = 0; i < 8; ++i) {
        int f = tid + i * 256;
        int r = f >> 7, k = f & 127;
        int gr = row0 + r;
        xs[r][k] = (gr < N) ? x[(size_t)gr * FIN + k] : 0.f;
    }
    __syncthreads();
    float acc[TM1];
    #pragma unroll
    for (int r = 0; r < TM1; ++r) acc[r] = 0.f;
    const int j = tid;
    for (int k = 0; k < FIN; k += 4) {
        float w0 = W1[(size_t)(k + 0) * C1 + j];
        float w1 = W1[(size_t)(k + 1) * C1 + j];
        float w2 = W1[(size_t)(k + 2) * C1 + j];
        float w3 = W1[(size_t)(k + 3) * C1 + j];
        #pragma unroll
        for (int r = 0; r < TM1; ++r) {
            float4 xv = *reinterpret_cast<const float4*>(&xs[r][k]);
            acc[r] = fmaf(xv.x, w0, acc[r]);
            acc[r] = fmaf(xv.y, w1, acc[r]);
            acc[r] = fmaf(xv.z, w2, acc[r]);
            acc[r] = fmaf(xv.w, w3, acc[r]);
        }
    }
    int hd = j >> 5, d = j & 31;
    float asw = att_s[hd * HD + d], adw = att_d[hd * HD + d];
    #pragma unroll
    for (int r = 0; r < TM1; ++r) {
        int row = row0 + r;
        if (row >= N) break;
        float v = acc[r];
        h1[(size_t)row * C1 + j] = __float2bfloat16(v);
        float ps = v * asw, pd = v * adw;
        #pragma unroll
        for (int m = 16; m >= 1; m >>= 1) {
            ps += __shfl_xor(ps, m, 64);
            pd += __shfl_xor(pd, m, 64);
        }
        if (d == 0) { as1[row * NH + hd] = ps; ad1[row * NH + hd] = pd; }
    }
}

// Layer-1 aggregation: ONE WAVE per node. Softmax bookkeeping in 8-lane head
// groups (h=lane>>3). Gather: 2 edges/iter — half=lane>>5 picks edge parity,
// lane owns dims (lane&31)*8..+7 (16B uint4 loads, 1KB/wave-instr); per-head
// scale/denom fetched via shfl from the softmax group.
__global__ __launch_bounds__(256) void agg1_kernel(
    const int* __restrict__ rowptr, const int* __restrict__ colb,
    const float* __restrict__ as1, const float* __restrict__ ad1,
    const __hip_bfloat16* __restrict__ h1, const float* __restrict__ b1,
    float* __restrict__ x1e, int N) {
    int wid = threadIdx.x >> 6, lane = threadIdx.x & 63;
    int n = blockIdx.x * 4 + wid;
    __shared__ float sp[4][CH1 * 9];
    __shared__ int ssrc[4][CH1];
    __shared__ float advs[4][NH];
    if (n >= N) return;
    int start = rowptr[n], end = rowptr[n + 1];
    int h = lane >> 3, sub = lane & 7;       // softmax mapping
    int half = lane >> 5, l5 = lane & 31;    // gather mapping
    int hq = l5 >> 2;                        // head of owned dims l5*8..l5*8+7
    ssrc[wid][lane] = 0;                     // safe stale index for e==cn reads
    if (lane < NH) advs[wid][lane] = ad1[n * NH + lane];
    float adr[NH];
    #pragma unroll
    for (int hh = 0; hh < NH; ++hh) adr[hh] = advs[wid][hh];

    float m = -INFINITY, denom = 0.f;
    float a0 = 0.f, a1 = 0.f, a2 = 0.f, a3 = 0.f;
    float a4 = 0.f, a5 = 0.f, a6 = 0.f, a7 = 0.f;
    for (int base = start; base < end; base += CH1) {
        int cn = min(CH1, end - base);
        if (lane < cn) {
            int s = colb[base + lane];
            ssrc[wid][lane] = s;
            const float4* ap = reinterpret_cast<const float4*>(as1 + (size_t)s * NH);
            float4 q0 = ap[0], q1 = ap[1];
            float av[8] = {q0.x, q0.y, q0.z, q0.w, q1.x, q1.y, q1.z, q1.w};
            #pragma unroll
            for (int hh = 0; hh < NH; ++hh) {
                float e = av[hh] + adr[hh];
                e = e > 0.f ? e : 0.2f * e;
                sp[wid][lane * 9 + hh] = e;
            }
        }
        // per-head chunk max (8-lane groups, masks 4,2,1)
        float cmax = -INFINITY;
        for (int e = sub; e < cn; e += 8) cmax = fmaxf(cmax, sp[wid][e * 9 + h]);
        #pragma unroll
        for (int mk = 4; mk >= 1; mk >>= 1) cmax = fmaxf(cmax, __shfl_xor(cmax, mk, 64));
        float newm = fmaxf(m, cmax);
        float scale = __expf(m - newm);
        float scale_g = __shfl(scale, hq << 3, 64);   // my dims' head scale
        a0 *= scale_g; a1 *= scale_g; a2 *= scale_g; a3 *= scale_g;
        a4 *= scale_g; a5 *= scale_g; a6 *= scale_g; a7 *= scale_g;
        denom *= scale; m = newm;
        float psum = 0.f;
        for (int e = sub; e < cn; e += 8) {
            float p = __expf(sp[wid][e * 9 + h] - m);
            sp[wid][e * 9 + h] = p;
            psum += p;
        }
        #pragma unroll
        for (int mk = 4; mk >= 1; mk >>= 1) psum += __shfl_xor(psum, mk, 64);
        denom += psum;
        // gather: 2 edges/iter, 16B/lane (1KB per wave-instruction)
        #pragma unroll 2
        for (int e2 = 0; e2 < cn; e2 += 2) {
            int e = e2 + half;
            bool ok = e < cn;
            int s = ssrc[wid][ok ? e : 0];
            float p = ok ? sp[wid][e * 9 + hq] : 0.f;
            uint4 u = *reinterpret_cast<const uint4*>(h1 + (size_t)s * C1 + l5 * 8);
            a0 = fmaf(p, blo(u.x), a0);
            a1 = fmaf(p, bhi(u.x), a1);
            a2 = fmaf(p, blo(u.y), a2);
            a3 = fmaf(p, bhi(u.y), a3);
            a4 = fmaf(p, blo(u.z), a4);
            a5 = fmaf(p, bhi(u.z), a5);
            a6 = fmaf(p, blo(u.w), a6);
            a7 = fmaf(p, bhi(u.w), a7);
        }
    }
    // combine edge-parity halves
    a0 += __shfl_xor(a0, 32, 64); a1 += __shfl_xor(a1, 32, 64);
    a2 += __shfl_xor(a2, 32, 64); a3 += __shfl_xor(a3, 32, 64);
    a4 += __shfl_xor(a4, 32, 64); a5 += __shfl_xor(a5, 32, 64);
    a6 += __shfl_xor(a6, 32, 64); a7 += __shfl_xor(a7, 32, 64);
    float invd = 1.f / __shfl(denom, hq << 3, 64);
    if (half == 0) {
        const float4* bp = reinterpret_cast<const float4*>(b1 + l5 * 8);
        float4 bv0 = bp[0], bv1 = bp[1];
        float v0 = a0 * invd + bv0.x, v1 = a1 * invd + bv0.y;
        float v2 = a2 * invd + bv0.z, v3 = a3 * invd + bv0.w;
        float v4 = a4 * invd + bv1.x, v5 = a5 * invd + bv1.y;
        float v6 = a6 * invd + bv1.z, v7 = a7 * invd + bv1.w;
        float4 o0, o1;
        o0.x = v0 > 0.f ? v0 : __expf(v0) - 1.f;
        o0.y = v1 > 0.f ? v1 : __expf(v1) - 1.f;
        o0.z = v2 > 0.f ? v2 : __expf(v2) - 1.f;
        o0.w = v3 > 0.f ? v3 : __expf(v3) - 1.f;
        o1.x = v4 > 0.f ? v4 : __expf(v4) - 1.f;
        o1.y = v5 > 0.f ? v5 : __expf(v5) - 1.f;
        o1.z = v6 > 0.f ? v6 : __expf(v6) - 1.f;
        o1.w = v7 > 0.f ? v7 : __expf(v7) - 1.f;
        float4* op = reinterpret_cast<float4*>(x1e + (size_t)n * C1 + l5 * 8);
        op[0] = o0; op[1] = o1;
    }
}

// h2 = x1e @ W2 [N,64] stored bf16, plus a_s2/a_d2 (H=1) in f32
__global__ __launch_bounds__(256) void gemm2_kernel(
    const float* __restrict__ x1e, const float* __restrict__ W2,
    const float* __restrict__ att_s2, const float* __restrict__ att_d2,
    __hip_bfloat16* __restrict__ h2, float* __restrict__ as2, float* __restrict__ ad2, int N) {
    __shared__ float xs[16][C1];
    int tid = threadIdx.x;
    int row0 = blockIdx.x * 16;
    #pragma unroll
    for (int i = 0; i < 16; ++i) {
        int f = tid + i * 256;
        int r = f >> 8, k = f & 255;
        int gr = row0 + r;
        xs[r][k] = (gr < N) ? x1e[(size_t)gr * C1 + k] : 0.f;
    }
    __syncthreads();
    int j = tid & 63, rg = tid >> 6;
    float acc[4] = {0.f, 0.f, 0.f, 0.f};
    for (int k = 0; k < C1; k += 4) {
        float w0 = W2[(size_t)(k + 0) * C2 + j];
        float w1 = W2[(size_t)(k + 1) * C2 + j];
        float w2v = W2[(size_t)(k + 2) * C2 + j];
        float w3 = W2[(size_t)(k + 3) * C2 + j];
        #pragma unroll
        for (int r = 0; r < 4; ++r) {
            float4 xv = *reinterpret_cast<const float4*>(&xs[rg * 4 + r][k]);
            acc[r] = fmaf(xv.x, w0, acc[r]);
            acc[r] = fmaf(xv.y, w1, acc[r]);
            acc[r] = fmaf(xv.z, w2v, acc[r]);
            acc[r] = fmaf(xv.w, w3, acc[r]);
        }
    }
    float asw = att_s2[j], adw = att_d2[j];
    #pragma unroll
    for (int r = 0; r < 4; ++r) {
        int row = row0 + rg * 4 + r;
        if (row >= N) break;
        float v = acc[r];
        h2[(size_t)row * C2 + j] = __float2bfloat16(v);
        float ps = v * asw, pd = v * adw;
        #pragma unroll
        for (int m = 32; m >= 1; m >>= 1) {
            ps += __shfl_xor(ps, m, 64);
            pd += __shfl_xor(pd, m, 64);
        }
        if (j == 0) { as2[row] = ps; ad2[row] = pd; }
    }
}

// Layer-2 aggregation + bias + log_softmax. One wave per node.
// Gather: 4 edges/iter — 16-lane groups (q=lane>>4), lane owns dims
// (lane&15)*4..+3 (8B uint2 loads, 512B/wave-instr).
__global__ __launch_bounds__(256) void agg2_kernel(
    const int* __restrict__ rowptr, const int* __restrict__ colb,
    const float* __restrict__ as2, const float* __restrict__ ad2,
    const __hip_bfloat16* __restrict__ h2, const float* __restrict__ b2,
    float* __restrict__ out, int N) {
    int wid = threadIdx.x >> 6, lane = threadIdx.x & 63;
    int n = blockIdx.x * 4 + wid;
    __shared__ float sp2[4][64];
    __shared__ int ssrc2[4][64];
    if (n >= N) return;
    int start = rowptr[n], end = rowptr[n + 1];
    int q = lane >> 4, l4 = lane & 15;
    ssrc2[wid][lane] = 0;
    float adn = ad2[n];
    float m = -INFINITY, denom = 0.f;
    float a0 = 0.f, a1 = 0.f, a2 = 0.f, a3 = 0.f;
    for (int base = start; base < end; base += 64) {
        int cn = min(64, end - base);
        float logit = -INFINITY;
        if (lane < cn) {
            int s = colb[base + lane];
            ssrc2[wid][lane] = s;
            float e = as2[s] + adn;
            logit = e > 0.f ? e : 0.2f * e;
        }
        float cmax = logit;
        #pragma unroll
        for (int mk = 32; mk >= 1; mk >>= 1) cmax = fmaxf(cmax, __shfl_xor(cmax, mk, 64));
        float newm = fmaxf(m, cmax);
        float scale = __expf(m - newm);
        a0 *= scale; a1 *= scale; a2 *= scale; a3 *= scale;
        denom *= scale; m = newm;
        float p = (lane < cn) ? __expf(logit - m) : 0.f;
        sp2[wid][lane] = p;
        float psum = p;
        #pragma unroll
        for (int mk = 32; mk >= 1; mk >>= 1) psum += __shfl_xor(psum, mk, 64);
        denom += psum;
        #pragma unroll 2
        for (int e2 = 0; e2 < cn; e2 += 4) {
            int e = e2 + q;
            bool ok = e < cn;
            int s = ssrc2[wid][ok ? e : 0];
            float pe = ok ? sp2[wid][e] : 0.f;
            uint2 u = *reinterpret_cast<const uint2*>(h2 + (size_t)s * C2 + l4 * 4);
            a0 = fmaf(pe, blo(u.x), a0);
            a1 = fmaf(pe, bhi(u.x), a1);
            a2 = fmaf(pe, blo(u.y), a2);
            a3 = fmaf(pe, bhi(u.y), a3);
        }
    }
    // combine 4 edge-quarter groups
    a0 += __shfl_xor(a0, 16, 64); a1 += __shfl_xor(a1, 16, 64);
    a2 += __shfl_xor(a2, 16, 64); a3 += __shfl_xor(a3, 16, 64);
    a0 += __shfl_xor(a0, 32, 64); a1 += __shfl_xor(a1, 32, 64);
    a2 += __shfl_xor(a2, 32, 64); a3 += __shfl_xor(a3, 32, 64);
    float invd = 1.f / denom;
    const float4* bp = reinterpret_cast<const float4*>(b2 + l4 * 4);
    float4 bv = bp[0];
    float v0 = a0 * invd + bv.x, v1 = a1 * invd + bv.y;
    float v2 = a2 * invd + bv.z, v3 = a3 * invd + bv.w;
    // log_softmax over 64 dims (4/lane across 16-lane groups; groups duplicated)
    float mx = fmaxf(fmaxf(v0, v1), fmaxf(v2, v3));
    #pragma unroll
    for (int mk = 8; mk >= 1; mk >>= 1) mx = fmaxf(mx, __shfl_xor(mx, mk, 64));
    float sum = __expf(v0 - mx) + __expf(v1 - mx) + __expf(v2 - mx) + __expf(v3 - mx);
    #pragma unroll
    for (int mk = 8; mk >= 1; mk >>= 1) sum += __shfl_xor(sum, mk, 64);
    float ls = logf(sum);
    if (q == 0) {
        float4 o = make_float4(v0 - mx - ls, v1 - mx - ls, v2 - mx - ls, v3 - mx - ls);
        *reinterpret_cast<float4*>(out + (size_t)n * C2 + l4 * 4) = o;
    }
}

extern "C" void kernel_launch(void* const* d_in, const int* in_sizes, int n_in,
                              void* d_out, int out_size, void* d_ws, size_t ws_size,
                              hipStream_t stream) {
    const float* x      = (const float*)d_in[0];
    const int*   ei     = (const int*)d_in[1];
    const float* W1     = (const float*)d_in[2];
    const float* att_s1 = (const float*)d_in[3];
    const float* att_d1 = (const float*)d_in[4];
    const float* b1     = (const float*)d_in[5];
    const float* W2     = (const float*)d_in[6];
    const float* att_s2 = (const float*)d_in[7];
    const float* att_d2 = (const float*)d_in[8];
    const float* b2     = (const float*)d_in[9];
    float* out = (float*)d_out;

    const int N = out_size / C2;          // 50000
    const int E = in_sizes[1] / 2;        // 1.6M
    const int ETOT = E + N;
    const int NB = (N + 255) / 256;       // scan blocks

    char* ws = (char*)d_ws;
    size_t off = 0;
    auto alloc = [&](size_t bytes) -> void* {
        void* p = ws + off;
        off += (bytes + 255) & ~(size_t)255;
        return p;
    };
    __hip_bfloat16* h1 = (__hip_bfloat16*)alloc((size_t)N * C1 * 2);   // 25.6 MB
    float* x1e  = (float*)alloc((size_t)N * C1 * 4);                   // 51.2 MB
    float* as1  = (float*)alloc((size_t)N * NH * 4);
    float* ad1  = (float*)alloc((size_t)N * NH * 4);
    float* as2  = (float*)alloc((size_t)N * 4);
    float* ad2  = (float*)alloc((size_t)N * 4);
    int*   cnt    = (int*)alloc((size_t)N * 4);
    int*   rowptr = (int*)alloc((size_t)(N + 1) * 4);
    int*   pref   = (int*)alloc((size_t)N * 4);
    int*   bsum   = (int*)alloc((size_t)NB * 4);
    int*   offs   = (int*)alloc((size_t)ETOT * 4);   // 6.6 MB
    int*   colb   = (int*)alloc((size_t)ETOT * 4);   // 6.6 MB
    __hip_bfloat16* h2 = h1;   // h1 dead after agg1; reuse for h2 [N,64] bf16

    // --- CSR build (by dst), atomic-rank + two-level scan, no scatter atomics ---
    const int T = (ETOT + 3) / 4;   // edges per stride
    zero_kernel<<<(N + 255) / 256, 256, 0, stream>>>(cnt, N);
    hist_kernel<<<(T + 255) / 256, 256, 0, stream>>>(ei, E, ETOT, T, cnt, offs);
    scan1_kernel<<<NB, 256, 0, stream>>>(cnt, N, pref, bsum);
    scan2_kernel<<<1, 256, 0, stream>>>(bsum, NB);
    scan3_kernel<<<NB, 256, 0, stream>>>(pref, bsum, N, ETOT, rowptr);
    scatter_kernel<<<(T + 255) / 256, 256, 0, stream>>>(ei, rowptr, offs, E, ETOT, T, colb);

    // --- Layer 1 ---
    gemm1_kernel<<<(N + TM1 - 1) / TM1, 256, 0, stream>>>(x, W1, att_s1, att_d1,
                                                          h1, as1, ad1, N);
    agg1_kernel<<<(N + 3) / 4, 256, 0, stream>>>(rowptr, colb, as1, ad1, h1, b1, x1e, N);

    // --- Layer 2 ---
    gemm2_kernel<<<(N + 15) / 16, 256, 0, stream>>>(x1e, W2, att_s2, att_d2,
                                                    h2, as2, ad2, N);
    agg2_kernel<<<(N + 3) / 4, 256, 0, stream>>>(rowptr, colb, as2, ad2, h2, b2, out, N);
}

// Round 7
// 346.708 us; speedup vs baseline: 1.1682x; 1.1682x over previous
//
#include <hip/hip_runtime.h>
#include <hip/hip_bf16.h>
#include <math.h>

// GAT 2-layer forward for MI355X.
// R7: agg1's random-gather path is saturated at ~3.75 TB/s (R5 vs R6: two
// different structures, identical BW) -> reduce BYTES: h1 stored fp8 e4m3
// (256B rows, HW cvt_pk_f32_fp8 unpack); x1e stored bf16.

#define FIN 128
#define C1 256   // H*D layer1
#define NH 8
#define HD 32
#define C2 64    // F_out
#define TM1 16
#define CH1 64

typedef float floatx2 __attribute__((ext_vector_type(2)));

__device__ __forceinline__ float blo(unsigned u) { return __uint_as_float(u << 16); }
__device__ __forceinline__ float bhi(unsigned u) { return __uint_as_float(u & 0xffff0000u); }
// pack 2 f32 -> 2 bf16 (RNE), low word = a
__device__ __forceinline__ unsigned pkbf(float a, float b) {
    unsigned ua = __float_as_uint(a), ub = __float_as_uint(b);
    ua += 0x7fff + ((ua >> 16) & 1);
    ub += 0x7fff + ((ub >> 16) & 1);
    return (ua >> 16) | (ub & 0xffff0000u);
}

__global__ void zero_kernel(int* p, int n) {
    int i = blockIdx.x * 256 + threadIdx.x;
    if (i < n) p[i] = 0;
}

// 4 edges/thread: count in-degree AND record each edge's rank within its dst.
__global__ void hist_kernel(const int* __restrict__ ei, int E, int ETOT, int T,
                            int* cnt, int* __restrict__ offs) {
    int base = blockIdx.x * 256 + threadIdx.x;
    if (base >= T) return;              // stride period is T: no duplicates
    int d[4], idx[4], o[4];
    #pragma unroll
    for (int i = 0; i < 4; ++i) {
        int e = base + i * T;
        idx[i] = e;
        d[i] = (e < ETOT) ? ((e < E) ? ei[E + e] : (e - E)) : -1;
    }
    #pragma unroll
    for (int i = 0; i < 4; ++i)
        if (d[i] >= 0) o[i] = atomicAdd(&cnt[d[i]], 1);
    #pragma unroll
    for (int i = 0; i < 4; ++i)
        if (d[i] >= 0) offs[idx[i]] = o[i];
}

// Two-level exclusive scan over cnt[0..n).
__global__ void scan1_kernel(const int* __restrict__ cnt, int n,
                             int* __restrict__ pref, int* __restrict__ bsum) {
    int tid = threadIdx.x, lane = tid & 63, w = tid >> 6;
    int i = blockIdx.x * 256 + tid;
    int v = (i < n) ? cnt[i] : 0;
    int sc = v;
    #pragma unroll
    for (int d = 1; d < 64; d <<= 1) {
        int t = __shfl_up(sc, d, 64);
        if (lane >= d) sc += t;
    }
    __shared__ int ws[4];
    if (lane == 63) ws[w] = sc;
    __syncthreads();
    int woff = 0;
    #pragma unroll
    for (int k = 0; k < 4; ++k) woff += (k < w) ? ws[k] : 0;
    if (i < n) pref[i] = woff + sc - v;
    if (tid == 255) bsum[blockIdx.x] = woff + sc;
}

__global__ void scan2_kernel(int* bsum, int nb) {
    int tid = threadIdx.x, lane = tid & 63, w = tid >> 6;
    int v = (tid < nb) ? bsum[tid] : 0;
    int sc = v;
    #pragma unroll
    for (int d = 1; d < 64; d <<= 1) {
        int t = __shfl_up(sc, d, 64);
        if (lane >= d) sc += t;
    }
    __shared__ int ws[4];
    if (lane == 63) ws[w] = sc;
    __syncthreads();
    int woff = 0;
    #pragma unroll
    for (int k = 0; k < 4; ++k) woff += (k < w) ? ws[k] : 0;
    __syncthreads();
    if (tid < nb) bsum[tid] = woff + sc - v;
}

__global__ void scan3_kernel(const int* __restrict__ pref, const int* __restrict__ bsum,
                             int n, int ETOT, int* __restrict__ rowptr) {
    int i = blockIdx.x * 256 + threadIdx.x;
    if (i < n) rowptr[i] = pref[i] + bsum[blockIdx.x];
    if (i == 0) rowptr[n] = ETOT;
}

// No atomics: pos = rowptr[dst] + offs[e]. 4 edges/thread.
__global__ void scatter_kernel(const int* __restrict__ ei, const int* __restrict__ rowptr,
                               const int* __restrict__ offs, int E, int ETOT, int T,
                               int* __restrict__ colb) {
    int base = blockIdx.x * 256 + threadIdx.x;
    if (base >= T) return;
    #pragma unroll
    for (int i = 0; i < 4; ++i) {
        int e = base + i * T;
        if (e >= ETOT) continue;
        int src, dst;
        if (e < E) { src = ei[e]; dst = ei[E + e]; }
        else       { src = e - E; dst = e - E; }
        colb[rowptr[dst] + offs[e]] = src;
    }
}

// h1 = x @ W1  [N,256] stored fp8 e4m3, plus a_s1/a_d1 per (node, head) in f32
__global__ __launch_bounds__(256) void gemm1_kernel(
    const float* __restrict__ x, const float* __restrict__ W1,
    const float* __restrict__ att_s, const float* __restrict__ att_d,
    unsigned char* __restrict__ h1, float* __restrict__ as1, float* __restrict__ ad1, int N) {
    __shared__ float xs[TM1][FIN];
    int tid = threadIdx.x;
    int row0 = blockIdx.x * TM1;
    #pragma unroll
    for (int i = 0; i < 8; ++i) {
        int f = tid + i * 256;
        int r = f >> 7, k = f & 127;
        int gr = row0 + r;
        xs[r][k] = (gr < N) ? x[(size_t)gr * FIN + k] : 0.f;
    }
    __syncthreads();
    float acc[TM1];
    #pragma unroll
    for (int r = 0; r < TM1; ++r) acc[r] = 0.f;
    const int j = tid;
    for (int k = 0; k < FIN; k += 4) {
        float w0 = W1[(size_t)(k + 0) * C1 + j];
        float w1 = W1[(size_t)(k + 1) * C1 + j];
        float w2 = W1[(size_t)(k + 2) * C1 + j];
        float w3 = W1[(size_t)(k + 3) * C1 + j];
        #pragma unroll
        for (int r = 0; r < TM1; ++r) {
            float4 xv = *reinterpret_cast<const float4*>(&xs[r][k]);
            acc[r] = fmaf(xv.x, w0, acc[r]);
            acc[r] = fmaf(xv.y, w1, acc[r]);
            acc[r] = fmaf(xv.z, w2, acc[r]);
            acc[r] = fmaf(xv.w, w3, acc[r]);
        }
    }
    int hd = j >> 5, d = j & 31;
    float asw = att_s[hd * HD + d], adw = att_d[hd * HD + d];
    #pragma unroll
    for (int r = 0; r < TM1; ++r) {
        int row = row0 + r;
        if (row >= N) break;
        float v = acc[r];
        unsigned pk = __builtin_amdgcn_cvt_pk_fp8_f32(v, v, 0, false);
        h1[(size_t)row * C1 + j] = (unsigned char)(pk & 0xff);
        float ps = v * asw, pd = v * adw;
        #pragma unroll
        for (int m = 16; m >= 1; m >>= 1) {
            ps += __shfl_xor(ps, m, 64);
            pd += __shfl_xor(pd, m, 64);
        }
        if (d == 0) { as1[row * NH + hd] = ps; ad1[row * NH + hd] = pd; }
    }
}

// Layer-1 aggregation: ONE WAVE per node. Softmax in 8-lane head groups.
// Gather: fp8 rows (256B), 2 edges/iter, 8B/lane, HW cvt_pk_f32_fp8 unpack.
// Output x1e stored bf16.
__global__ __launch_bounds__(256) void agg1_kernel(
    const int* __restrict__ rowptr, const int* __restrict__ colb,
    const float* __restrict__ as1, const float* __restrict__ ad1,
    const unsigned char* __restrict__ h1, const float* __restrict__ b1,
    __hip_bfloat16* __restrict__ x1e, int N) {
    int wid = threadIdx.x >> 6, lane = threadIdx.x & 63;
    int n = blockIdx.x * 4 + wid;
    __shared__ float sp[4][CH1 * 9];
    __shared__ int ssrc[4][CH1];
    __shared__ float advs[4][NH];
    if (n >= N) return;
    int start = rowptr[n], end = rowptr[n + 1];
    int h = lane >> 3, sub = lane & 7;       // softmax mapping
    int half = lane >> 5, l5 = lane & 31;    // gather mapping
    int hq = l5 >> 2;                        // head of owned dims l5*8..l5*8+7
    ssrc[wid][lane] = 0;
    if (lane < NH) advs[wid][lane] = ad1[n * NH + lane];
    float adr[NH];
    #pragma unroll
    for (int hh = 0; hh < NH; ++hh) adr[hh] = advs[wid][hh];

    float m = -INFINITY, denom = 0.f;
    float a0 = 0.f, a1 = 0.f, a2 = 0.f, a3 = 0.f;
    float a4 = 0.f, a5 = 0.f, a6 = 0.f, a7 = 0.f;
    for (int base = start; base < end; base += CH1) {
        int cn = min(CH1, end - base);
        if (lane < cn) {
            int s = colb[base + lane];
            ssrc[wid][lane] = s;
            const float4* ap = reinterpret_cast<const float4*>(as1 + (size_t)s * NH);
            float4 q0 = ap[0], q1 = ap[1];
            float av[8] = {q0.x, q0.y, q0.z, q0.w, q1.x, q1.y, q1.z, q1.w};
            #pragma unroll
            for (int hh = 0; hh < NH; ++hh) {
                float e = av[hh] + adr[hh];
                e = e > 0.f ? e : 0.2f * e;
                sp[wid][lane * 9 + hh] = e;
            }
        }
        float cmax = -INFINITY;
        for (int e = sub; e < cn; e += 8) cmax = fmaxf(cmax, sp[wid][e * 9 + h]);
        #pragma unroll
        for (int mk = 4; mk >= 1; mk >>= 1) cmax = fmaxf(cmax, __shfl_xor(cmax, mk, 64));
        float newm = fmaxf(m, cmax);
        float scale = __expf(m - newm);
        float scale_g = __shfl(scale, hq << 3, 64);
        a0 *= scale_g; a1 *= scale_g; a2 *= scale_g; a3 *= scale_g;
        a4 *= scale_g; a5 *= scale_g; a6 *= scale_g; a7 *= scale_g;
        denom *= scale; m = newm;
        float psum = 0.f;
        for (int e = sub; e < cn; e += 8) {
            float p = __expf(sp[wid][e * 9 + h] - m);
            sp[wid][e * 9 + h] = p;
            psum += p;
        }
        #pragma unroll
        for (int mk = 4; mk >= 1; mk >>= 1) psum += __shfl_xor(psum, mk, 64);
        denom += psum;
        // gather: 2 edges/iter, fp8 rows, 8B/lane (512B per wave-instruction)
        #pragma unroll 2
        for (int e2 = 0; e2 < cn; e2 += 2) {
            int e = e2 + half;
            bool ok = e < cn;
            int s = ssrc[wid][ok ? e : 0];
            float p = ok ? sp[wid][e * 9 + hq] : 0.f;
            uint2 u = *reinterpret_cast<const uint2*>(h1 + (size_t)s * C1 + l5 * 8);
            floatx2 f01 = __builtin_amdgcn_cvt_pk_f32_fp8((int)u.x, false);
            floatx2 f23 = __builtin_amdgcn_cvt_pk_f32_fp8((int)u.x, true);
            floatx2 f45 = __builtin_amdgcn_cvt_pk_f32_fp8((int)u.y, false);
            floatx2 f67 = __builtin_amdgcn_cvt_pk_f32_fp8((int)u.y, true);
            a0 = fmaf(p, f01.x, a0);
            a1 = fmaf(p, f01.y, a1);
            a2 = fmaf(p, f23.x, a2);
            a3 = fmaf(p, f23.y, a3);
            a4 = fmaf(p, f45.x, a4);
            a5 = fmaf(p, f45.y, a5);
            a6 = fmaf(p, f67.x, a6);
            a7 = fmaf(p, f67.y, a7);
        }
    }
    a0 += __shfl_xor(a0, 32, 64); a1 += __shfl_xor(a1, 32, 64);
    a2 += __shfl_xor(a2, 32, 64); a3 += __shfl_xor(a3, 32, 64);
    a4 += __shfl_xor(a4, 32, 64); a5 += __shfl_xor(a5, 32, 64);
    a6 += __shfl_xor(a6, 32, 64); a7 += __shfl_xor(a7, 32, 64);
    float invd = 1.f / __shfl(denom, hq << 3, 64);
    if (half == 0) {
        const float4* bp = reinterpret_cast<const float4*>(b1 + l5 * 8);
        float4 bv0 = bp[0], bv1 = bp[1];
        float v0 = a0 * invd + bv0.x, v1 = a1 * invd + bv0.y;
        float v2 = a2 * invd + bv0.z, v3 = a3 * invd + bv0.w;
        float v4 = a4 * invd + bv1.x, v5 = a5 * invd + bv1.y;
        float v6 = a6 * invd + bv1.z, v7 = a7 * invd + bv1.w;
        v0 = v0 > 0.f ? v0 : __expf(v0) - 1.f;
        v1 = v1 > 0.f ? v1 : __expf(v1) - 1.f;
        v2 = v2 > 0.f ? v2 : __expf(v2) - 1.f;
        v3 = v3 > 0.f ? v3 : __expf(v3) - 1.f;
        v4 = v4 > 0.f ? v4 : __expf(v4) - 1.f;
        v5 = v5 > 0.f ? v5 : __expf(v5) - 1.f;
        v6 = v6 > 0.f ? v6 : __expf(v6) - 1.f;
        v7 = v7 > 0.f ? v7 : __expf(v7) - 1.f;
        uint4 w;
        w.x = pkbf(v0, v1); w.y = pkbf(v2, v3);
        w.z = pkbf(v4, v5); w.w = pkbf(v6, v7);
        *reinterpret_cast<uint4*>(x1e + (size_t)n * C1 + l5 * 8) = w;
    }
}

// h2 = x1e @ W2 [N,64] stored bf16 (x1e read as bf16), plus a_s2/a_d2 (H=1)
__global__ __launch_bounds__(256) void gemm2_kernel(
    const __hip_bfloat16* __restrict__ x1e, const float* __restrict__ W2,
    const float* __restrict__ att_s2, const float* __restrict__ att_d2,
    __hip_bfloat16* __restrict__ h2, float* __restrict__ as2, float* __restrict__ ad2, int N) {
    __shared__ float xs[16][C1];
    int tid = threadIdx.x;
    int row0 = blockIdx.x * 16;
    const unsigned* xv = reinterpret_cast<const unsigned*>(x1e);
    #pragma unroll
    for (int i = 0; i < 8; ++i) {
        int p = tid + i * 256;         // pair index, 2048 pairs total
        int r = p >> 7, cp = p & 127;  // row in tile, col pair
        int gr = row0 + r;
        unsigned u = (gr < N) ? xv[(size_t)gr * 128 + cp] : 0u;
        xs[r][cp * 2] = blo(u);
        xs[r][cp * 2 + 1] = bhi(u);
    }
    __syncthreads();
    int j = tid & 63, rg = tid >> 6;
    float acc[4] = {0.f, 0.f, 0.f, 0.f};
    for (int k = 0; k < C1; k += 4) {
        float w0 = W2[(size_t)(k + 0) * C2 + j];
        float w1 = W2[(size_t)(k + 1) * C2 + j];
        float w2v = W2[(size_t)(k + 2) * C2 + j];
        float w3 = W2[(size_t)(k + 3) * C2 + j];
        #pragma unroll
        for (int r = 0; r < 4; ++r) {
            float4 xvv = *reinterpret_cast<const float4*>(&xs[rg * 4 + r][k]);
            acc[r] = fmaf(xvv.x, w0, acc[r]);
            acc[r] = fmaf(xvv.y, w1, acc[r]);
            acc[r] = fmaf(xvv.z, w2v, acc[r]);
            acc[r] = fmaf(xvv.w, w3, acc[r]);
        }
    }
    float asw = att_s2[j], adw = att_d2[j];
    #pragma unroll
    for (int r = 0; r < 4; ++r) {
        int row = row0 + rg * 4 + r;
        if (row >= N) break;
        float v = acc[r];
        h2[(size_t)row * C2 + j] = __float2bfloat16(v);
        float ps = v * asw, pd = v * adw;
        #pragma unroll
        for (int m = 32; m >= 1; m >>= 1) {
            ps += __shfl_xor(ps, m, 64);
            pd += __shfl_xor(pd, m, 64);
        }
        if (j == 0) { as2[row] = ps; ad2[row] = pd; }
    }
}

// Layer-2 aggregation + bias + log_softmax. One wave per node, 4 edges/iter.
__global__ __launch_bounds__(256) void agg2_kernel(
    const int* __restrict__ rowptr, const int* __restrict__ colb,
    const float* __restrict__ as2, const float* __restrict__ ad2,
    const __hip_bfloat16* __restrict__ h2, const float* __restrict__ b2,
    float* __restrict__ out, int N) {
    int wid = threadIdx.x >> 6, lane = threadIdx.x & 63;
    int n = blockIdx.x * 4 + wid;
    __shared__ float sp2[4][64];
    __shared__ int ssrc2[4][64];
    if (n >= N) return;
    int start = rowptr[n], end = rowptr[n + 1];
    int q = lane >> 4, l4 = lane & 15;
    ssrc2[wid][lane] = 0;
    float adn = ad2[n];
    float m = -INFINITY, denom = 0.f;
    float a0 = 0.f, a1 = 0.f, a2 = 0.f, a3 = 0.f;
    for (int base = start; base < end; base += 64) {
        int cn = min(64, end - base);
        float logit = -INFINITY;
        if (lane < cn) {
            int s = colb[base + lane];
            ssrc2[wid][lane] = s;
            float e = as2[s] + adn;
            logit = e > 0.f ? e : 0.2f * e;
        }
        float cmax = logit;
        #pragma unroll
        for (int mk = 32; mk >= 1; mk >>= 1) cmax = fmaxf(cmax, __shfl_xor(cmax, mk, 64));
        float newm = fmaxf(m, cmax);
        float scale = __expf(m - newm);
        a0 *= scale; a1 *= scale; a2 *= scale; a3 *= scale;
        denom *= scale; m = newm;
        float p = (lane < cn) ? __expf(logit - m) : 0.f;
        sp2[wid][lane] = p;
        float psum = p;
        #pragma unroll
        for (int mk = 32; mk >= 1; mk >>= 1) psum += __shfl_xor(psum, mk, 64);
        denom += psum;
        #pragma unroll 2
        for (int e2 = 0; e2 < cn; e2 += 4) {
            int e = e2 + q;
            bool ok = e < cn;
            int s = ssrc2[wid][ok ? e : 0];
            float pe = ok ? sp2[wid][e] : 0.f;
            uint2 u = *reinterpret_cast<const uint2*>(h2 + (size_t)s * C2 + l4 * 4);
            a0 = fmaf(pe, blo(u.x), a0);
            a1 = fmaf(pe, bhi(u.x), a1);
            a2 = fmaf(pe, blo(u.y), a2);
            a3 = fmaf(pe, bhi(u.y), a3);
        }
    }
    a0 += __shfl_xor(a0, 16, 64); a1 += __shfl_xor(a1, 16, 64);
    a2 += __shfl_xor(a2, 16, 64); a3 += __shfl_xor(a3, 16, 64);
    a0 += __shfl_xor(a0, 32, 64); a1 += __shfl_xor(a1, 32, 64);
    a2 += __shfl_xor(a2, 32, 64); a3 += __shfl_xor(a3, 32, 64);
    float invd = 1.f / denom;
    const float4* bp = reinterpret_cast<const float4*>(b2 + l4 * 4);
    float4 bv = bp[0];
    float v0 = a0 * invd + bv.x, v1 = a1 * invd + bv.y;
    float v2 = a2 * invd + bv.z, v3 = a3 * invd + bv.w;
    float mx = fmaxf(fmaxf(v0, v1), fmaxf(v2, v3));
    #pragma unroll
    for (int mk = 8; mk >= 1; mk >>= 1) mx = fmaxf(mx, __shfl_xor(mx, mk, 64));
    float sum = __expf(v0 - mx) + __expf(v1 - mx) + __expf(v2 - mx) + __expf(v3 - mx);
    #pragma unroll
    for (int mk = 8; mk >= 1; mk >>= 1) sum += __shfl_xor(sum, mk, 64);
    float ls = logf(sum);
    if (q == 0) {
        float4 o = make_float4(v0 - mx - ls, v1 - mx - ls, v2 - mx - ls, v3 - mx - ls);
        *reinterpret_cast<float4*>(out + (size_t)n * C2 + l4 * 4) = o;
    }
}

extern "C" void kernel_launch(void* const* d_in, const int* in_sizes, int n_in,
                              void* d_out, int out_size, void* d_ws, size_t ws_size,
                              hipStream_t stream) {
    const float* x      = (const float*)d_in[0];
    const int*   ei     = (const int*)d_in[1];
    const float* W1     = (const float*)d_in[2];
    const float* att_s1 = (const float*)d_in[3];
    const float* att_d1 = (const float*)d_in[4];
    const float* b1     = (const float*)d_in[5];
    const float* W2     = (const float*)d_in[6];
    const float* att_s2 = (const float*)d_in[7];
    const float* att_d2 = (const float*)d_in[8];
    const float* b2     = (const float*)d_in[9];
    float* out = (float*)d_out;

    const int N = out_size / C2;          // 50000
    const int E = in_sizes[1] / 2;        // 1.6M
    const int ETOT = E + N;
    const int NB = (N + 255) / 256;       // scan blocks

    char* ws = (char*)d_ws;
    size_t off = 0;
    auto alloc = [&](size_t bytes) -> void* {
        void* p = ws + off;
        off += (bytes + 255) & ~(size_t)255;
        return p;
    };
    unsigned char* h1 = (unsigned char*)alloc((size_t)N * C1);           // 12.8 MB fp8
    __hip_bfloat16* x1e = (__hip_bfloat16*)alloc((size_t)N * C1 * 2);    // 25.6 MB bf16
    float* as1  = (float*)alloc((size_t)N * NH * 4);
    float* ad1  = (float*)alloc((size_t)N * NH * 4);
    float* as2  = (float*)alloc((size_t)N * 4);
    float* ad2  = (float*)alloc((size_t)N * 4);
    int*   cnt    = (int*)alloc((size_t)N * 4);
    int*   rowptr = (int*)alloc((size_t)(N + 1) * 4);
    int*   pref   = (int*)alloc((size_t)N * 4);
    int*   bsum   = (int*)alloc((size_t)NB * 4);
    int*   offs   = (int*)alloc((size_t)ETOT * 4);   // 6.6 MB
    int*   colb   = (int*)alloc((size_t)ETOT * 4);   // 6.6 MB
    __hip_bfloat16* h2 = (__hip_bfloat16*)h1;  // h1 dead after agg1; reuse (6.4MB needed <= 12.8MB)

    // --- CSR build (by dst), atomic-rank + two-level scan, no scatter atomics ---
    const int T = (ETOT + 3) / 4;   // edges per stride
    zero_kernel<<<(N + 255) / 256, 256, 0, stream>>>(cnt, N);
    hist_kernel<<<(T + 255) / 256, 256, 0, stream>>>(ei, E, ETOT, T, cnt, offs);
    scan1_kernel<<<NB, 256, 0, stream>>>(cnt, N, pref, bsum);
    scan2_kernel<<<1, 256, 0, stream>>>(bsum, NB);
    scan3_kernel<<<NB, 256, 0, stream>>>(pref, bsum, N, ETOT, rowptr);
    scatter_kernel<<<(T + 255) / 256, 256, 0, stream>>>(ei, rowptr, offs, E, ETOT, T, colb);

    // --- Layer 1 ---
    gemm1_kernel<<<(N + TM1 - 1) / TM1, 256, 0, stream>>>(x, W1, att_s1, att_d1,
                                                          h1, as1, ad1, N);
    agg1_kernel<<<(N + 3) / 4, 256, 0, stream>>>(rowptr, colb, as1, ad1, h1, b1, x1e, N);

    // --- Layer 2 ---
    gemm2_kernel<<<(N + 15) / 16, 256, 0, stream>>>(x1e, W2, att_s2, att_d2,
                                                    h2, as2, ad2, N);
    agg2_kernel<<<(N + 3) / 4, 256, 0, stream>>>(rowptr, colb, as2, ad2, h2, b2, out, N);
}

// Round 8
// 297.305 us; speedup vs baseline: 1.3623x; 1.1662x over previous
//
#include <hip/hip_runtime.h>
#include <hip/hip_bf16.h>
#include <math.h>

// GAT 2-layer forward for MI355X.
// R8: both GEMMs converted to bf16 MFMA (16x16x32). gemm1 was LDS-bound FP32
// VALU (101us, 32TF). A-tiles staged in XOR-swizzled LDS; W transposed to
// [out][k] bf16 so B-frags are contiguous. h1 stored fp8 from C-frags;
// attention coeffs computed by separate coalesced row-scan kernels.

#define FIN 128
#define C1 256   // H*D layer1
#define NH 8
#define HD 32
#define C2 64    // F_out
#define CH1 64

typedef float floatx2 __attribute__((ext_vector_type(2)));
typedef short bf16x8 __attribute__((ext_vector_type(8)));
typedef float f32x4 __attribute__((ext_vector_type(4)));

__device__ __forceinline__ float blo(unsigned u) { return __uint_as_float(u << 16); }
__device__ __forceinline__ float bhi(unsigned u) { return __uint_as_float(u & 0xffff0000u); }
__device__ __forceinline__ unsigned pkbf(float a, float b) {
    unsigned ua = __float_as_uint(a), ub = __float_as_uint(b);
    ua += 0x7fff + ((ua >> 16) & 1);
    ub += 0x7fff + ((ub >> 16) & 1);
    return (ua >> 16) | (ub & 0xffff0000u);
}

__global__ void zero_kernel(int* p, int n) {
    int i = blockIdx.x * 256 + threadIdx.x;
    if (i < n) p[i] = 0;
}

__global__ void hist_kernel(const int* __restrict__ ei, int E, int ETOT, int T,
                            int* cnt, int* __restrict__ offs) {
    int base = blockIdx.x * 256 + threadIdx.x;
    if (base >= T) return;
    int d[4], idx[4], o[4];
    #pragma unroll
    for (int i = 0; i < 4; ++i) {
        int e = base + i * T;
        idx[i] = e;
        d[i] = (e < ETOT) ? ((e < E) ? ei[E + e] : (e - E)) : -1;
    }
    #pragma unroll
    for (int i = 0; i < 4; ++i)
        if (d[i] >= 0) o[i] = atomicAdd(&cnt[d[i]], 1);
    #pragma unroll
    for (int i = 0; i < 4; ++i)
        if (d[i] >= 0) offs[idx[i]] = o[i];
}

__global__ void scan1_kernel(const int* __restrict__ cnt, int n,
                             int* __restrict__ pref, int* __restrict__ bsum) {
    int tid = threadIdx.x, lane = tid & 63, w = tid >> 6;
    int i = blockIdx.x * 256 + tid;
    int v = (i < n) ? cnt[i] : 0;
    int sc = v;
    #pragma unroll
    for (int d = 1; d < 64; d <<= 1) {
        int t = __shfl_up(sc, d, 64);
        if (lane >= d) sc += t;
    }
    __shared__ int ws[4];
    if (lane == 63) ws[w] = sc;
    __syncthreads();
    int woff = 0;
    #pragma unroll
    for (int k = 0; k < 4; ++k) woff += (k < w) ? ws[k] : 0;
    if (i < n) pref[i] = woff + sc - v;
    if (tid == 255) bsum[blockIdx.x] = woff + sc;
}

__global__ void scan2_kernel(int* bsum, int nb) {
    int tid = threadIdx.x, lane = tid & 63, w = tid >> 6;
    int v = (tid < nb) ? bsum[tid] : 0;
    int sc = v;
    #pragma unroll
    for (int d = 1; d < 64; d <<= 1) {
        int t = __shfl_up(sc, d, 64);
        if (lane >= d) sc += t;
    }
    __shared__ int ws[4];
    if (lane == 63) ws[w] = sc;
    __syncthreads();
    int woff = 0;
    #pragma unroll
    for (int k = 0; k < 4; ++k) woff += (k < w) ? ws[k] : 0;
    __syncthreads();
    if (tid < nb) bsum[tid] = woff + sc - v;
}

__global__ void scan3_kernel(const int* __restrict__ pref, const int* __restrict__ bsum,
                             int n, int ETOT, int* __restrict__ rowptr) {
    int i = blockIdx.x * 256 + threadIdx.x;
    if (i < n) rowptr[i] = pref[i] + bsum[blockIdx.x];
    if (i == 0) rowptr[n] = ETOT;
}

__global__ void scatter_kernel(const int* __restrict__ ei, const int* __restrict__ rowptr,
                               const int* __restrict__ offs, int E, int ETOT, int T,
                               int* __restrict__ colb) {
    int base = blockIdx.x * 256 + threadIdx.x;
    if (base >= T) return;
    #pragma unroll
    for (int i = 0; i < 4; ++i) {
        int e = base + i * T;
        if (e >= ETOT) continue;
        int src, dst;
        if (e < E) { src = ei[e]; dst = ei[E + e]; }
        else       { src = e - E; dst = e - E; }
        colb[rowptr[dst] + offs[e]] = src;
    }
}

// ---- dtype prep ----
__global__ void cvt_x_kernel(const float* __restrict__ x, unsigned* __restrict__ xb, int total8) {
    int i = blockIdx.x * 256 + threadIdx.x;
    if (i >= total8) return;
    const float4* p = reinterpret_cast<const float4*>(x + (size_t)i * 8);
    float4 v0 = p[0], v1 = p[1];
    uint4 o;
    o.x = pkbf(v0.x, v0.y); o.y = pkbf(v0.z, v0.w);
    o.z = pkbf(v1.x, v1.y); o.w = pkbf(v1.z, v1.w);
    reinterpret_cast<uint4*>(xb)[i] = o;
}

// W1 [128][256] f32 -> w1t [256][128] bf16
__global__ void cvt_w1_kernel(const float* __restrict__ W1, unsigned short* __restrict__ w1t) {
    int k = blockIdx.x, j = threadIdx.x;
    float v = W1[k * C1 + j];
    w1t[j * FIN + k] = (unsigned short)(pkbf(v, v) & 0xffffu);
}

// W2 [256][64] f32 -> w2t [64][256] bf16
__global__ void cvt_w2_kernel(const float* __restrict__ W2, unsigned short* __restrict__ w2t) {
    int j = blockIdx.x, k = threadIdx.x;
    float v = W2[k * C2 + j];
    w2t[j * C1 + k] = (unsigned short)(pkbf(v, v) & 0xffffu);
}

// ---- gemm1: h1[N,256] fp8 = xb[N,128] @ w1t^T, MFMA 16x16x32 ----
__global__ __launch_bounds__(256) void gemm1_mfma(
    const unsigned short* __restrict__ xb, const unsigned short* __restrict__ w1t,
    unsigned char* __restrict__ h1, int Nn) {
    __shared__ __align__(16) unsigned char sA[64 * 256];   // 64 rows x 256B, swizzled
    int tid = threadIdx.x;
    int row0 = blockIdx.x * 64;
    #pragma unroll
    for (int rep = 0; rep < 4; ++rep) {
        int flat = rep * 256 + tid;          // 1024 chunks of 16B
        int row = flat >> 4, c16 = flat & 15;
        uint4 v = make_uint4(0u, 0u, 0u, 0u);
        if (row0 + row < Nn)
            v = *reinterpret_cast<const uint4*>(
                reinterpret_cast<const unsigned char*>(xb) + (size_t)(row0 + row) * 256 + c16 * 16);
        *reinterpret_cast<uint4*>(sA + ((row * 256 + c16 * 16) ^ ((row & 7) << 4))) = v;
    }
    __syncthreads();
    int w = tid >> 6, l = tid & 63;
    int lr = l & 15, lq = l >> 4;
    int arow = w * 16 + lr;
    bf16x8 a[4];
    #pragma unroll
    for (int ks = 0; ks < 4; ++ks)
        a[ks] = *reinterpret_cast<const bf16x8*>(
            sA + ((arow * 256 + ks * 64 + lq * 16) ^ ((arow & 7) << 4)));
    const unsigned char* wb = reinterpret_cast<const unsigned char*>(w1t);
    #pragma unroll
    for (int nt = 0; nt < 16; ++nt) {
        f32x4 acc = {0.f, 0.f, 0.f, 0.f};
        #pragma unroll
        for (int ks = 0; ks < 4; ++ks) {
            bf16x8 b = *reinterpret_cast<const bf16x8*>(
                wb + (size_t)(nt * 16 + lr) * 256 + ks * 64 + lq * 16);
            acc = __builtin_amdgcn_mfma_f32_16x16x32_bf16(a[ks], b, acc, 0, 0, 0);
        }
        int col = nt * 16 + lr;
        #pragma unroll
        for (int reg = 0; reg < 4; ++reg) {
            int row = row0 + w * 16 + lq * 4 + reg;
            if (row < Nn) {
                unsigned pk = __builtin_amdgcn_cvt_pk_fp8_f32(acc[reg], acc[reg], 0, false);
                h1[(size_t)row * C1 + col] = (unsigned char)(pk & 0xffu);
            }
        }
    }
}

// a_s1/a_d1 from fp8 h1: block = 16 rows, 16 lanes per row (16 cols each).
__global__ __launch_bounds__(256) void att1_kernel(
    const unsigned char* __restrict__ h1, const float* __restrict__ att_s,
    const float* __restrict__ att_d, float* __restrict__ as1, float* __restrict__ ad1, int Nn) {
    int tid = threadIdx.x;
    int row = blockIdx.x * 16 + (tid >> 4);
    int l16 = tid & 15;
    if (row >= Nn) return;
    uint4 u = *reinterpret_cast<const uint4*>(h1 + (size_t)row * C1 + l16 * 16);
    float hv[16];
    unsigned uu[4] = {u.x, u.y, u.z, u.w};
    #pragma unroll
    for (int q = 0; q < 4; ++q) {
        floatx2 f0 = __builtin_amdgcn_cvt_pk_f32_fp8((int)uu[q], false);
        floatx2 f1 = __builtin_amdgcn_cvt_pk_f32_fp8((int)uu[q], true);
        hv[q * 4 + 0] = f0.x; hv[q * 4 + 1] = f0.y;
        hv[q * 4 + 2] = f1.x; hv[q * 4 + 3] = f1.y;
    }
    int col0 = l16 * 16;
    const float4* asp = reinterpret_cast<const float4*>(att_s + col0);
    const float4* adp = reinterpret_cast<const float4*>(att_d + col0);
    float ps = 0.f, pd = 0.f;
    #pragma unroll
    for (int q = 0; q < 4; ++q) {
        float4 sa = asp[q], da = adp[q];
        ps += hv[q*4+0]*sa.x + hv[q*4+1]*sa.y + hv[q*4+2]*sa.z + hv[q*4+3]*sa.w;
        pd += hv[q*4+0]*da.x + hv[q*4+1]*da.y + hv[q*4+2]*da.z + hv[q*4+3]*da.w;
    }
    ps += __shfl_xor(ps, 1, 64);     // combine the two half-head lanes
    pd += __shfl_xor(pd, 1, 64);
    if ((l16 & 1) == 0) {
        as1[row * NH + (l16 >> 1)] = ps;
        ad1[row * NH + (l16 >> 1)] = pd;
    }
}

// Layer-1 aggregation (unchanged from R7): fp8 gather, softmax per head.
__global__ __launch_bounds__(256) void agg1_kernel(
    const int* __restrict__ rowptr, const int* __restrict__ colb,
    const float* __restrict__ as1, const float* __restrict__ ad1,
    const unsigned char* __restrict__ h1, const float* __restrict__ b1,
    __hip_bfloat16* __restrict__ x1e, int N) {
    int wid = threadIdx.x >> 6, lane = threadIdx.x & 63;
    int n = blockIdx.x * 4 + wid;
    __shared__ float sp[4][CH1 * 9];
    __shared__ int ssrc[4][CH1];
    __shared__ float advs[4][NH];
    if (n >= N) return;
    int start = rowptr[n], end = rowptr[n + 1];
    int h = lane >> 3, sub = lane & 7;
    int half = lane >> 5, l5 = lane & 31;
    int hq = l5 >> 2;
    ssrc[wid][lane] = 0;
    if (lane < NH) advs[wid][lane] = ad1[n * NH + lane];
    float adr[NH];
    #pragma unroll
    for (int hh = 0; hh < NH; ++hh) adr[hh] = advs[wid][hh];

    float m = -INFINITY, denom = 0.f;
    float a0 = 0.f, a1 = 0.f, a2 = 0.f, a3 = 0.f;
    float a4 = 0.f, a5 = 0.f, a6 = 0.f, a7 = 0.f;
    for (int base = start; base < end; base += CH1) {
        int cn = min(CH1, end - base);
        if (lane < cn) {
            int s = colb[base + lane];
            ssrc[wid][lane] = s;
            const float4* ap = reinterpret_cast<const float4*>(as1 + (size_t)s * NH);
            float4 q0 = ap[0], q1 = ap[1];
            float av[8] = {q0.x, q0.y, q0.z, q0.w, q1.x, q1.y, q1.z, q1.w};
            #pragma unroll
            for (int hh = 0; hh < NH; ++hh) {
                float e = av[hh] + adr[hh];
                e = e > 0.f ? e : 0.2f * e;
                sp[wid][lane * 9 + hh] = e;
            }
        }
        float cmax = -INFINITY;
        for (int e = sub; e < cn; e += 8) cmax = fmaxf(cmax, sp[wid][e * 9 + h]);
        #pragma unroll
        for (int mk = 4; mk >= 1; mk >>= 1) cmax = fmaxf(cmax, __shfl_xor(cmax, mk, 64));
        float newm = fmaxf(m, cmax);
        float scale = __expf(m - newm);
        float scale_g = __shfl(scale, hq << 3, 64);
        a0 *= scale_g; a1 *= scale_g; a2 *= scale_g; a3 *= scale_g;
        a4 *= scale_g; a5 *= scale_g; a6 *= scale_g; a7 *= scale_g;
        denom *= scale; m = newm;
        float psum = 0.f;
        for (int e = sub; e < cn; e += 8) {
            float p = __expf(sp[wid][e * 9 + h] - m);
            sp[wid][e * 9 + h] = p;
            psum += p;
        }
        #pragma unroll
        for (int mk = 4; mk >= 1; mk >>= 1) psum += __shfl_xor(psum, mk, 64);
        denom += psum;
        #pragma unroll 2
        for (int e2 = 0; e2 < cn; e2 += 2) {
            int e = e2 + half;
            bool ok = e < cn;
            int s = ssrc[wid][ok ? e : 0];
            float p = ok ? sp[wid][e * 9 + hq] : 0.f;
            uint2 u = *reinterpret_cast<const uint2*>(h1 + (size_t)s * C1 + l5 * 8);
            floatx2 f01 = __builtin_amdgcn_cvt_pk_f32_fp8((int)u.x, false);
            floatx2 f23 = __builtin_amdgcn_cvt_pk_f32_fp8((int)u.x, true);
            floatx2 f45 = __builtin_amdgcn_cvt_pk_f32_fp8((int)u.y, false);
            floatx2 f67 = __builtin_amdgcn_cvt_pk_f32_fp8((int)u.y, true);
            a0 = fmaf(p, f01.x, a0);
            a1 = fmaf(p, f01.y, a1);
            a2 = fmaf(p, f23.x, a2);
            a3 = fmaf(p, f23.y, a3);
            a4 = fmaf(p, f45.x, a4);
            a5 = fmaf(p, f45.y, a5);
            a6 = fmaf(p, f67.x, a6);
            a7 = fmaf(p, f67.y, a7);
        }
    }
    a0 += __shfl_xor(a0, 32, 64); a1 += __shfl_xor(a1, 32, 64);
    a2 += __shfl_xor(a2, 32, 64); a3 += __shfl_xor(a3, 32, 64);
    a4 += __shfl_xor(a4, 32, 64); a5 += __shfl_xor(a5, 32, 64);
    a6 += __shfl_xor(a6, 32, 64); a7 += __shfl_xor(a7, 32, 64);
    float invd = 1.f / __shfl(denom, hq << 3, 64);
    if (half == 0) {
        const float4* bp = reinterpret_cast<const float4*>(b1 + l5 * 8);
        float4 bv0 = bp[0], bv1 = bp[1];
        float v0 = a0 * invd + bv0.x, v1 = a1 * invd + bv0.y;
        float v2 = a2 * invd + bv0.z, v3 = a3 * invd + bv0.w;
        float v4 = a4 * invd + bv1.x, v5 = a5 * invd + bv1.y;
        float v6 = a6 * invd + bv1.z, v7 = a7 * invd + bv1.w;
        v0 = v0 > 0.f ? v0 : __expf(v0) - 1.f;
        v1 = v1 > 0.f ? v1 : __expf(v1) - 1.f;
        v2 = v2 > 0.f ? v2 : __expf(v2) - 1.f;
        v3 = v3 > 0.f ? v3 : __expf(v3) - 1.f;
        v4 = v4 > 0.f ? v4 : __expf(v4) - 1.f;
        v5 = v5 > 0.f ? v5 : __expf(v5) - 1.f;
        v6 = v6 > 0.f ? v6 : __expf(v6) - 1.f;
        v7 = v7 > 0.f ? v7 : __expf(v7) - 1.f;
        uint4 w;
        w.x = pkbf(v0, v1); w.y = pkbf(v2, v3);
        w.z = pkbf(v4, v5); w.w = pkbf(v6, v7);
        *reinterpret_cast<uint4*>(x1e + (size_t)n * C1 + l5 * 8) = w;
    }
}

// ---- gemm2: h2[N,64] bf16 = x1e[N,256] @ w2t^T, MFMA 16x16x32 ----
__global__ __launch_bounds__(256) void gemm2_mfma(
    const unsigned short* __restrict__ x1e, const unsigned short* __restrict__ w2t,
    unsigned short* __restrict__ h2, int Nn) {
    __shared__ __align__(16) unsigned char sA[64 * 512];   // 64 rows x 512B, swizzled
    int tid = threadIdx.x;
    int row0 = blockIdx.x * 64;
    #pragma unroll
    for (int rep = 0; rep < 8; ++rep) {
        int flat = rep * 256 + tid;          // 2048 chunks of 16B
        int row = flat >> 5, c16 = flat & 31;
        uint4 v = make_uint4(0u, 0u, 0u, 0u);
        if (row0 + row < Nn)
            v = *reinterpret_cast<const uint4*>(
                reinterpret_cast<const unsigned char*>(x1e) + (size_t)(row0 + row) * 512 + c16 * 16);
        *reinterpret_cast<uint4*>(sA + ((row * 512 + c16 * 16) ^ ((row & 7) << 4))) = v;
    }
    __syncthreads();
    int w = tid >> 6, l = tid & 63;
    int lr = l & 15, lq = l >> 4;
    int arow = w * 16 + lr;
    bf16x8 a[8];
    #pragma unroll
    for (int ks = 0; ks < 8; ++ks)
        a[ks] = *reinterpret_cast<const bf16x8*>(
            sA + ((arow * 512 + ks * 64 + lq * 16) ^ ((arow & 7) << 4)));
    const unsigned char* wb = reinterpret_cast<const unsigned char*>(w2t);
    #pragma unroll
    for (int nt = 0; nt < 4; ++nt) {
        f32x4 acc = {0.f, 0.f, 0.f, 0.f};
        #pragma unroll
        for (int ks = 0; ks < 8; ++ks) {
            bf16x8 b = *reinterpret_cast<const bf16x8*>(
                wb + (size_t)(nt * 16 + lr) * 512 + ks * 64 + lq * 16);
            acc = __builtin_amdgcn_mfma_f32_16x16x32_bf16(a[ks], b, acc, 0, 0, 0);
        }
        int col = nt * 16 + lr;
        #pragma unroll
        for (int reg = 0; reg < 4; ++reg) {
            int row = row0 + w * 16 + lq * 4 + reg;
            if (row < Nn)
                h2[(size_t)row * C2 + col] = (unsigned short)(pkbf(acc[reg], acc[reg]) & 0xffffu);
        }
    }
}

// a_s2/a_d2 from bf16 h2 (H=1): 16 lanes per row, 4 cols each.
__global__ __launch_bounds__(256) void att2_kernel(
    const unsigned short* __restrict__ h2, const float* __restrict__ att_s2,
    const float* __restrict__ att_d2, float* __restrict__ as2, float* __restrict__ ad2, int Nn) {
    int tid = threadIdx.x;
    int row = blockIdx.x * 16 + (tid >> 4);
    int l16 = tid & 15;
    if (row >= Nn) return;
    uint2 u = *reinterpret_cast<const uint2*>(h2 + (size_t)row * C2 + l16 * 4);
    float h0 = blo(u.x), h1v = bhi(u.x), h2v = blo(u.y), h3 = bhi(u.y);
    const float4* asp = reinterpret_cast<const float4*>(att_s2 + l16 * 4);
    const float4* adp = reinterpret_cast<const float4*>(att_d2 + l16 * 4);
    float4 sa = asp[0], da = adp[0];
    float ps = h0*sa.x + h1v*sa.y + h2v*sa.z + h3*sa.w;
    float pd = h0*da.x + h1v*da.y + h2v*da.z + h3*da.w;
    #pragma unroll
    for (int mk = 8; mk >= 1; mk >>= 1) {
        ps += __shfl_xor(ps, mk, 64);
        pd += __shfl_xor(pd, mk, 64);
    }
    if (l16 == 0) { as2[row] = ps; ad2[row] = pd; }
}

// Layer-2 aggregation + bias + log_softmax (unchanged from R7).
__global__ __launch_bounds__(256) void agg2_kernel(
    const int* __restrict__ rowptr, const int* __restrict__ colb,
    const float* __restrict__ as2, const float* __restrict__ ad2,
    const __hip_bfloat16* __restrict__ h2, const float* __restrict__ b2,
    float* __restrict__ out, int N) {
    int wid = threadIdx.x >> 6, lane = threadIdx.x & 63;
    int n = blockIdx.x * 4 + wid;
    __shared__ float sp2[4][64];
    __shared__ int ssrc2[4][64];
    if (n >= N) return;
    int start = rowptr[n], end = rowptr[n + 1];
    int q = lane >> 4, l4 = lane & 15;
    ssrc2[wid][lane] = 0;
    float adn = ad2[n];
    float m = -INFINITY, denom = 0.f;
    float a0 = 0.f, a1 = 0.f, a2 = 0.f, a3 = 0.f;
    for (int base = start; base < end; base += 64) {
        int cn = min(64, end - base);
        float logit = -INFINITY;
        if (lane < cn) {
            int s = colb[base + lane];
            ssrc2[wid][lane] = s;
            float e = as2[s] + adn;
            logit = e > 0.f ? e : 0.2f * e;
        }
        float cmax = logit;
        #pragma unroll
        for (int mk = 32; mk >= 1; mk >>= 1) cmax = fmaxf(cmax, __shfl_xor(cmax, mk, 64));
        float newm = fmaxf(m, cmax);
        float scale = __expf(m - newm);
        a0 *= scale; a1 *= scale; a2 *= scale; a3 *= scale;
        denom *= scale; m = newm;
        float p = (lane < cn) ? __expf(logit - m) : 0.f;
        sp2[wid][lane] = p;
        float psum = p;
        #pragma unroll
        for (int mk = 32; mk >= 1; mk >>= 1) psum += __shfl_xor(psum, mk, 64);
        denom += psum;
        #pragma unroll 2
        for (int e2 = 0; e2 < cn; e2 += 4) {
            int e = e2 + q;
            bool ok = e < cn;
            int s = ssrc2[wid][ok ? e : 0];
            float pe = ok ? sp2[wid][e] : 0.f;
            uint2 u = *reinterpret_cast<const uint2*>(h2 + (size_t)s * C2 + l4 * 4);
            a0 = fmaf(pe, blo(u.x), a0);
            a1 = fmaf(pe, bhi(u.x), a1);
            a2 = fmaf(pe, blo(u.y), a2);
            a3 = fmaf(pe, bhi(u.y), a3);
        }
    }
    a0 += __shfl_xor(a0, 16, 64); a1 += __shfl_xor(a1, 16, 64);
    a2 += __shfl_xor(a2, 16, 64); a3 += __shfl_xor(a3, 16, 64);
    a0 += __shfl_xor(a0, 32, 64); a1 += __shfl_xor(a1, 32, 64);
    a2 += __shfl_xor(a2, 32, 64); a3 += __shfl_xor(a3, 32, 64);
    float invd = 1.f / denom;
    const float4* bp = reinterpret_cast<const float4*>(b2 + l4 * 4);
    float4 bv = bp[0];
    float v0 = a0 * invd + bv.x, v1 = a1 * invd + bv.y;
    float v2 = a2 * invd + bv.z, v3 = a3 * invd + bv.w;
    float mx = fmaxf(fmaxf(v0, v1), fmaxf(v2, v3));
    #pragma unroll
    for (int mk = 8; mk >= 1; mk >>= 1) mx = fmaxf(mx, __shfl_xor(mx, mk, 64));
    float sum = __expf(v0 - mx) + __expf(v1 - mx) + __expf(v2 - mx) + __expf(v3 - mx);
    #pragma unroll
    for (int mk = 8; mk >= 1; mk >>= 1) sum += __shfl_xor(sum, mk, 64);
    float ls = logf(sum);
    if (q == 0) {
        float4 o = make_float4(v0 - mx - ls, v1 - mx - ls, v2 - mx - ls, v3 - mx - ls);
        *reinterpret_cast<float4*>(out + (size_t)n * C2 + l4 * 4) = o;
    }
}

extern "C" void kernel_launch(void* const* d_in, const int* in_sizes, int n_in,
                              void* d_out, int out_size, void* d_ws, size_t ws_size,
                              hipStream_t stream) {
    const float* x      = (const float*)d_in[0];
    const int*   ei     = (const int*)d_in[1];
    const float* W1     = (const float*)d_in[2];
    const float* att_s1 = (const float*)d_in[3];
    const float* att_d1 = (const float*)d_in[4];
    const float* b1     = (const float*)d_in[5];
    const float* W2     = (const float*)d_in[6];
    const float* att_s2 = (const float*)d_in[7];
    const float* att_d2 = (const float*)d_in[8];
    const float* b2     = (const float*)d_in[9];
    float* out = (float*)d_out;

    const int N = out_size / C2;          // 50000
    const int E = in_sizes[1] / 2;        // 1.6M
    const int ETOT = E + N;
    const int NB = (N + 255) / 256;

    char* ws = (char*)d_ws;
    size_t off = 0;
    auto alloc = [&](size_t bytes) -> void* {
        void* p = ws + off;
        off += (bytes + 255) & ~(size_t)255;
        return p;
    };
    unsigned char* h1 = (unsigned char*)alloc((size_t)N * C1);           // 12.8 MB fp8
    __hip_bfloat16* x1e = (__hip_bfloat16*)alloc((size_t)N * C1 * 2);    // 25.6 MB bf16
    unsigned* xb = (unsigned*)alloc((size_t)N * FIN * 2);                // 12.8 MB bf16
    unsigned short* w1t = (unsigned short*)alloc((size_t)C1 * FIN * 2);  // 64 KB
    unsigned short* w2t = (unsigned short*)alloc((size_t)C2 * C1 * 2);   // 32 KB
    float* as1  = (float*)alloc((size_t)N * NH * 4);
    float* ad1  = (float*)alloc((size_t)N * NH * 4);
    float* as2  = (float*)alloc((size_t)N * 4);
    float* ad2  = (float*)alloc((size_t)N * 4);
    int*   cnt    = (int*)alloc((size_t)N * 4);
    int*   rowptr = (int*)alloc((size_t)(N + 1) * 4);
    int*   pref   = (int*)alloc((size_t)N * 4);
    int*   bsum   = (int*)alloc((size_t)NB * 4);
    int*   offs   = (int*)alloc((size_t)ETOT * 4);
    int*   colb   = (int*)alloc((size_t)ETOT * 4);
    unsigned short* h2 = (unsigned short*)h1;   // h1 dead after agg1; reuse (6.4MB <= 12.8MB)

    // --- CSR build ---
    const int T = (ETOT + 3) / 4;
    zero_kernel<<<(N + 255) / 256, 256, 0, stream>>>(cnt, N);
    hist_kernel<<<(T + 255) / 256, 256, 0, stream>>>(ei, E, ETOT, T, cnt, offs);
    scan1_kernel<<<NB, 256, 0, stream>>>(cnt, N, pref, bsum);
    scan2_kernel<<<1, 256, 0, stream>>>(bsum, NB);
    scan3_kernel<<<NB, 256, 0, stream>>>(pref, bsum, N, ETOT, rowptr);
    scatter_kernel<<<(T + 255) / 256, 256, 0, stream>>>(ei, rowptr, offs, E, ETOT, T, colb);

    // --- dtype prep ---
    int total8 = N * FIN / 8;
    cvt_x_kernel<<<(total8 + 255) / 256, 256, 0, stream>>>(x, xb, total8);
    cvt_w1_kernel<<<FIN, C1, 0, stream>>>(W1, w1t);
    cvt_w2_kernel<<<C2, C1, 0, stream>>>(W2, w2t);

    // --- Layer 1 ---
    gemm1_mfma<<<(N + 63) / 64, 256, 0, stream>>>((const unsigned short*)xb, w1t, h1, N);
    att1_kernel<<<(N + 15) / 16, 256, 0, stream>>>(h1, att_s1, att_d1, as1, ad1, N);
    agg1_kernel<<<(N + 3) / 4, 256, 0, stream>>>(rowptr, colb, as1, ad1, h1, b1, x1e, N);

    // --- Layer 2 ---
    gemm2_mfma<<<(N + 63) / 64, 256, 0, stream>>>((const unsigned short*)x1e, w2t, h2, N);
    att2_kernel<<<(N + 15) / 16, 256, 0, stream>>>(h2, att_s2, att_d2, as2, ad2, N);
    agg2_kernel<<<(N + 3) / 4, 256, 0, stream>>>(rowptr, colb, as2, ad2,
                                                 (const __hip_bfloat16*)h2, b2, out, N);
}